// Round 1
// baseline (33.227 us; speedup 1.0000x reference)
//
#include <hip/hip_runtime.h>

// Problem shape (fixed by reference setup_inputs)
#define BB 8
#define SS 8192
#define CC 256
#define SCHUNK 64
#define NCHUNK (SS / SCHUNK)   // 128 s-chunks per batch

// ws layout: [0..2047] per-(b,c) column sums, [2048] global sum of x^2
__global__ __launch_bounds__(256) void pcl_partial(const float* __restrict__ x,
                                                   float* __restrict__ ws_cols,
                                                   float* __restrict__ ws_x2) {
    const int blk   = blockIdx.x;
    const int b     = blk / NCHUNK;
    const int chunk = blk - b * NCHUNK;
    const int s0    = chunk * SCHUNK;
    const int t     = threadIdx.x;
    const int g     = t >> 6;   // row-group 0..3
    const int l     = t & 63;   // lane

    // Thread reads columns 4l..4l+3, rows s0+g, s0+g+4, ... (16 rows)
    const float4* p = reinterpret_cast<const float4*>(
        x + ((size_t)b * SS + (size_t)(s0 + g)) * CC) + l;

    float sx0 = 0.f, sx1 = 0.f, sx2 = 0.f, sx3 = 0.f, sq = 0.f;
    #pragma unroll
    for (int k = 0; k < SCHUNK / 4; ++k) {
        float4 v = p[(size_t)k * 4 * (CC / 4)];   // step 4 rows = 256 float4
        sx0 += v.x; sx1 += v.y; sx2 += v.z; sx3 += v.w;
        sq  += v.x * v.x + v.y * v.y + v.z * v.z + v.w * v.w;
    }

    // Combine the 4 row-groups' column partials through LDS (float4 stores,
    // contiguous per lane -> conflict-free; reads are stride-1 -> free).
    __shared__ float lsum[4][CC];
    *reinterpret_cast<float4*>(&lsum[g][l * 4]) = make_float4(sx0, sx1, sx2, sx3);

    // Wave-reduce sum of squares (64-lane wave)
    for (int off = 32; off > 0; off >>= 1) sq += __shfl_down(sq, off, 64);
    __shared__ float x2buf[4];
    if (l == 0) x2buf[g] = sq;
    __syncthreads();

    const float col = lsum[0][t] + lsum[1][t] + lsum[2][t] + lsum[3][t];
    atomicAdd(&ws_cols[b * CC + t], col);
    if (t == 0)
        atomicAdd(ws_x2, x2buf[0] + x2buf[1] + x2buf[2] + x2buf[3]);
}

__global__ __launch_bounds__(256) void pcl_final(const float* __restrict__ ws_cols,
                                                 const float* __restrict__ ws_x2,
                                                 float* __restrict__ out) {
    const int t = threadIdx.x;
    float acc = 0.f;
    #pragma unroll
    for (int i = 0; i < (BB * CC) / 256; ++i) {
        const float m = ws_cols[i * 256 + t] * (1.0f / SS);
        acc += m * m;
    }
    for (int off = 32; off > 0; off >>= 1) acc += __shfl_down(acc, off, 64);
    __shared__ float buf[4];
    if ((t & 63) == 0) buf[t >> 6] = acc;
    __syncthreads();
    if (t == 0) {
        const float sum_mean2 = buf[0] + buf[1] + buf[2] + buf[3];
        const float mean_x2   = ws_x2[0] * (1.0f / ((float)BB * SS * CC));
        out[0] = 0.2f * (mean_x2 - sum_mean2 * (1.0f / (BB * CC)));
    }
}

extern "C" void kernel_launch(void* const* d_in, const int* in_sizes, int n_in,
                              void* d_out, int out_size, void* d_ws, size_t ws_size,
                              hipStream_t stream) {
    const float* x = (const float*)d_in[0];
    float* ws_cols = (float*)d_ws;                 // 2048 floats
    float* ws_x2   = ws_cols + BB * CC;            // 1 float
    float* out     = (float*)d_out;

    hipMemsetAsync(d_ws, 0, (BB * CC + 1) * sizeof(float), stream);
    pcl_partial<<<BB * NCHUNK, 256, 0, stream>>>(x, ws_cols, ws_x2);
    pcl_final<<<1, 256, 0, stream>>>(ws_cols, ws_x2, out);
}

// Round 3
// 21.756 us; speedup vs baseline: 1.5273x; 1.5273x over previous
//
#include <hip/hip_runtime.h>

// Problem shape (fixed by reference setup_inputs)
#define BB 8
#define SS 8192
#define CC 256

#define NBLK1 512                       // 2 blocks/CU
#define CHUNKS_PER_B (NBLK1 / BB)       // 64 s-chunks per batch
#define SCHUNK (SS / CHUNKS_PER_B)      // 128 rows per block
#define ROWS_PER_THREAD (SCHUNK / 4)    // 32 float4 loads per thread

// ws layout: ws1[NBLK1][CC] per-block column partial sums (512 KB),
//            ws2[NBLK1]      per-block sum-of-squares partials (2 KB).
// Plain overwriting stores every call -> no init, no atomics, deterministic.

__global__ __launch_bounds__(256) void pcl_partial(const float* __restrict__ x,
                                                   float* __restrict__ ws1,
                                                   float* __restrict__ ws2) {
    const int blk = blockIdx.x;
    const int b     = blk >> 6;         // blk / CHUNKS_PER_B
    const int chunk = blk & 63;
    const int s0    = chunk * SCHUNK;
    const int t = threadIdx.x;
    const int g = t >> 6;               // row-group 0..3
    const int l = t & 63;               // lane

    // Wave g reads full contiguous 1 KB rows s0+g, s0+g+4, ... (32 rows)
    const float4* p = reinterpret_cast<const float4*>(
        x + ((size_t)b * SS + (size_t)(s0 + g)) * CC) + l;

    float sx0 = 0.f, sx1 = 0.f, sx2 = 0.f, sx3 = 0.f, sq = 0.f;
    #pragma unroll 8
    for (int k = 0; k < ROWS_PER_THREAD; ++k) {
        float4 v = p[(size_t)k * CC];   // advance 4 rows = 256 float4
        sx0 += v.x; sx1 += v.y; sx2 += v.z; sx3 += v.w;
        sq  += v.x * v.x + v.y * v.y + v.z * v.z + v.w * v.w;
    }

    // Combine the 4 row-groups' column partials through LDS.
    __shared__ float lsum[4][CC];
    *reinterpret_cast<float4*>(&lsum[g][l * 4]) = make_float4(sx0, sx1, sx2, sx3);

    // Wave-reduce sum of squares
    for (int off = 32; off > 0; off >>= 1) sq += __shfl_down(sq, off, 64);
    __shared__ float x2buf[4];
    if (l == 0) x2buf[g] = sq;
    __syncthreads();

    ws1[blk * CC + t] = lsum[0][t] + lsum[1][t] + lsum[2][t] + lsum[3][t];
    if (t == 0) ws2[blk] = x2buf[0] + x2buf[1] + x2buf[2] + x2buf[3];
}

__global__ __launch_bounds__(512) void pcl_final(const float* __restrict__ ws1,
                                                 const float* __restrict__ ws2,
                                                 float* __restrict__ out) {
    const int t  = threadIdx.x;         // 0..511
    const int b  = t >> 6;              // 0..7
    const int cq = t & 63;              // float4 column group

    // colsum[b][c] = sum over 64 chunk-partials; float4 per thread,
    // wave reads are 1 KB contiguous (L2-hot).
    const float4* p4 = reinterpret_cast<const float4*>(ws1)
                       + (size_t)b * CHUNKS_PER_B * (CC / 4) + cq;
    float4 s = make_float4(0.f, 0.f, 0.f, 0.f);
    #pragma unroll 8
    for (int chunk = 0; chunk < CHUNKS_PER_B; ++chunk) {
        float4 v = p4[(size_t)chunk * (CC / 4)];
        s.x += v.x; s.y += v.y; s.z += v.z; s.w += v.w;
    }
    const float inv_s = 1.0f / SS;
    const float m0 = s.x * inv_s, m1 = s.y * inv_s,
                m2 = s.z * inv_s, m3 = s.w * inv_s;

    // Fold both terms into one per-thread scalar:
    // loss = weight*2*( sum_x2/(B*S*C) - sum_mean2/(B*C) ), weight = 0.1
    float P = -(m0 * m0 + m1 * m1 + m2 * m2 + m3 * m3) * (1.0f / (BB * CC));
    P += ws2[t] * (1.0f / ((float)BB * SS * CC));   // exactly 512 partials

    for (int off = 32; off > 0; off >>= 1) P += __shfl_down(P, off, 64);
    __shared__ float buf[8];
    if ((t & 63) == 0) buf[t >> 6] = P;
    __syncthreads();
    if (t == 0) {
        float tot = 0.f;
        #pragma unroll
        for (int i = 0; i < 8; ++i) tot += buf[i];
        out[0] = 0.2f * tot;    // 0.1 (weight) * 2 (pairwise->variance identity)
    }
}

extern "C" void kernel_launch(void* const* d_in, const int* in_sizes, int n_in,
                              void* d_out, int out_size, void* d_ws, size_t ws_size,
                              hipStream_t stream) {
    const float* x = (const float*)d_in[0];
    float* ws1 = (float*)d_ws;              // 512*256 floats
    float* ws2 = ws1 + NBLK1 * CC;          // 512 floats
    float* out = (float*)d_out;

    pcl_partial<<<NBLK1, 256, 0, stream>>>(x, ws1, ws2);
    pcl_final<<<1, 512, 0, stream>>>(ws1, ws2, out);
}

// Round 4
// 20.995 us; speedup vs baseline: 1.5826x; 1.0362x over previous
//
#include <hip/hip_runtime.h>

// Problem shape (fixed by reference setup_inputs)
#define BB 8
#define SS 8192
#define CC 256

#define NBLK 256                        // 1 block per CU
#define CPB (NBLK / BB)                 // 32 s-chunks per batch
#define SCHUNK (SS / CPB)               // 256 rows per block
#define NW 16                           // waves per block (1024 threads)
#define ITERS (SCHUNK / NW)             // 16 float4 row-loads per thread

// ws layout: ws1[NBLK][CC] per-block column partial sums (256 KB),
//            ws2[NBLK]      per-block sum-of-squares partials (1 KB).
// Plain overwriting stores every call -> no init, no atomics, deterministic.

__global__ __launch_bounds__(1024) void pcl_partial(const float* __restrict__ x,
                                                    float* __restrict__ ws1,
                                                    float* __restrict__ ws2) {
    const int blk   = blockIdx.x;
    const int b     = blk >> 5;         // blk / CPB
    const int chunk = blk & 31;
    const int s0    = chunk * SCHUNK;
    const int t = threadIdx.x;
    const int w = t >> 6;               // wave 0..15
    const int l = t & 63;               // lane

    // Wave w reads full contiguous 1 KB rows s0+w, s0+w+16, ... (16 rows).
    // Block region = 256 contiguous rows = 256 KB sequential stream.
    const float4* p = reinterpret_cast<const float4*>(
        x + ((size_t)b * SS + (size_t)(s0 + w)) * CC) + l;

    float sx0 = 0.f, sx1 = 0.f, sx2 = 0.f, sx3 = 0.f, sq = 0.f;
    #pragma unroll 8
    for (int k = 0; k < ITERS; ++k) {
        float4 v = p[(size_t)k * (NW * CC / 4)];   // advance 16 rows
        sx0 += v.x; sx1 += v.y; sx2 += v.z; sx3 += v.w;
        sq  += v.x * v.x + v.y * v.y + v.z * v.z + v.w * v.w;
    }

    // Combine the 16 waves' column partials through LDS (16 KB).
    __shared__ float lsum[NW][CC];
    *reinterpret_cast<float4*>(&lsum[w][l * 4]) = make_float4(sx0, sx1, sx2, sx3);

    // Wave-reduce sum of squares
    for (int off = 32; off > 0; off >>= 1) sq += __shfl_down(sq, off, 64);
    __shared__ float x2buf[NW];
    if (l == 0) x2buf[w] = sq;
    __syncthreads();

    if (t < CC) {
        float col = 0.f;
        #pragma unroll
        for (int g = 0; g < NW; ++g) col += lsum[g][t];   // lanes contiguous -> no conflict
        ws1[blk * CC + t] = col;
    }
    if (t == 0) {
        float s2 = 0.f;
        #pragma unroll
        for (int g = 0; g < NW; ++g) s2 += x2buf[g];
        ws2[blk] = s2;
    }
}

__global__ __launch_bounds__(1024) void pcl_final(const float* __restrict__ ws1,
                                                  const float* __restrict__ ws2,
                                                  float* __restrict__ out) {
    const int t = threadIdx.x;          // 0..1023
    float P = 0.f;

    if (t < 512) {
        const int b  = t >> 6;          // 0..7
        const int cq = t & 63;          // float4 column group
        // colsum[b][4cq..4cq+3] = sum over 32 chunk-partials (L2/L3-hot).
        const float4* p4 = reinterpret_cast<const float4*>(ws1)
                           + (size_t)(b * CPB) * (CC / 4) + cq;
        float4 s = make_float4(0.f, 0.f, 0.f, 0.f);
        #pragma unroll 8
        for (int ch = 0; ch < CPB; ++ch) {
            float4 v = p4[(size_t)ch * (CC / 4)];
            s.x += v.x; s.y += v.y; s.z += v.z; s.w += v.w;
        }
        const float inv_s = 1.0f / SS;
        const float m0 = s.x * inv_s, m1 = s.y * inv_s,
                    m2 = s.z * inv_s, m3 = s.w * inv_s;
        P = -(m0 * m0 + m1 * m1 + m2 * m2 + m3 * m3) * (1.0f / (BB * CC));
    } else if (t < 512 + NBLK) {
        P = ws2[t - 512] * (1.0f / ((float)BB * SS * CC));
    }

    for (int off = 32; off > 0; off >>= 1) P += __shfl_down(P, off, 64);
    __shared__ float buf[16];
    if ((t & 63) == 0) buf[t >> 6] = P;
    __syncthreads();
    if (t == 0) {
        float tot = 0.f;
        #pragma unroll
        for (int i = 0; i < 16; ++i) tot += buf[i];
        out[0] = 0.2f * tot;    // 0.1 (weight) * 2 (pairwise->variance identity)
    }
}

extern "C" void kernel_launch(void* const* d_in, const int* in_sizes, int n_in,
                              void* d_out, int out_size, void* d_ws, size_t ws_size,
                              hipStream_t stream) {
    const float* x = (const float*)d_in[0];
    float* ws1 = (float*)d_ws;              // NBLK*CC floats
    float* ws2 = ws1 + NBLK * CC;           // NBLK floats
    float* out = (float*)d_out;

    pcl_partial<<<NBLK, 1024, 0, stream>>>(x, ws1, ws2);
    pcl_final<<<1, 1024, 0, stream>>>(ws1, ws2, out);
}